// Round 7
// baseline (364.888 us; speedup 1.0000x reference)
//
#include <hip/hip_runtime.h>
#include <math.h>

#define N   512
#define CS  384
#define CZ  128
#define H   12
#define C   16
#define P   4
#define PV  8
#define NB  64
#define KSP 528   // K-slice for k_out (2112/4)
#define QKD 28    // 16 (q·k) + 12 (qg·kg) fused dot length
#define QPAD 68   // d-major LDS row stride (k_qkpt)
#define APAD 516  // attn LDS row stride
#define ZPAD 132  // z-chunk LDS row stride (16B-aligned, conflict-tolerable)

// workspace offsets (in floats)
#define OFF_Q    0         // 512*192
#define OFF_K    98304     // 512*192
#define OFF_V    196608    // 512*192
#define OFF_QP   294912    // 512*144
#define OFF_KP   368640    // 512*144
#define OFF_VP   442368    // 512*288
#define OFF_QG   589824    // 512*144
#define OFF_KG   663552    // 512*144
#define OFF_VG   737280    // 512*288
#define OFF_QSQ  884736    // 512*12
#define OFF_KSQ  890880    // 512*12
#define OFF_LOG  897024    // 512*12*512  (raw qk+point logits only)
#define OFF_FEAT 4042752   // 512*2112

// ---------------- Kernel 1: all six projections (register-tiled GEMM) ----------
__global__ __launch_bounds__(256) void k_proj(
    const float* __restrict__ s,
    const float* __restrict__ Wq,  const float* __restrict__ bq,
    const float* __restrict__ Wk,  const float* __restrict__ bk,
    const float* __restrict__ Wv,  const float* __restrict__ bv,
    const float* __restrict__ Wqp, const float* __restrict__ bqp,
    const float* __restrict__ Wkp, const float* __restrict__ bkp,
    const float* __restrict__ Wvp, const float* __restrict__ bvp,
    float* __restrict__ ws)
{
    __shared__ float s_s[16*388];        // 24.8 KB
    __shared__ float part[4*16*68];      // 17.4 KB  (ks, row, col64 padded)
    const int tid = threadIdx.x;
    const int n0  = blockIdx.y * 16;
    const int cq  = tid & 15;
    const int rg  = (tid >> 4) & 3;
    const int ks  = tid >> 6;
    const int gc  = blockIdx.x * 64 + cq * 4;
    for (int i = tid; i < 16*384; i += 256) {
        int r = i / 384, c = i - r*384;
        s_s[r*388 + c] = s[(n0 + r)*384 + c];
    }
    __syncthreads();
    const float* W; int width; int lc;
    if      (gc < 192) { W=Wq;  width=192; lc=gc;     }
    else if (gc < 384) { W=Wk;  width=192; lc=gc-192; }
    else if (gc < 576) { W=Wv;  width=192; lc=gc-384; }
    else if (gc < 720) { W=Wqp; width=144; lc=gc-576; }
    else if (gc < 864) { W=Wkp; width=144; lc=gc-720; }
    else               { W=Wvp; width=288; lc=gc-864; }
    float acc[4][4] = {{0.f}};
    const float* wp   = W + lc + (size_t)(ks*96)*width;
    const float* srow = s_s + (rg*4)*388 + ks*96;
    #pragma unroll 4
    for (int kk = 0; kk < 96; kk++) {
        float4 w4 = *(const float4*)(wp + (size_t)kk*width);
        #pragma unroll
        for (int r = 0; r < 4; r++) {
            float sv = srow[r*388 + kk];
            acc[r][0] += sv*w4.x; acc[r][1] += sv*w4.y;
            acc[r][2] += sv*w4.z; acc[r][3] += sv*w4.w;
        }
    }
    #pragma unroll
    for (int r = 0; r < 4; r++)
        *(float4*)(part + (ks*16 + rg*4 + r)*68 + cq*4) =
            make_float4(acc[r][0], acc[r][1], acc[r][2], acc[r][3]);
    __syncthreads();
    {   // 256 threads: (row = tid>>4, same cq) sum 4 K-partials + bias, store
        const int row = tid >> 4;
        float4 sum = *(const float4*)(part + (0*16 + row)*68 + cq*4);
        #pragma unroll
        for (int k2 = 1; k2 < 4; k2++) {
            float4 p = *(const float4*)(part + (k2*16 + row)*68 + cq*4);
            sum.x += p.x; sum.y += p.y; sum.z += p.z; sum.w += p.w;
        }
        const float* b; float* dst; int w2, lc2;
        if      (gc < 192) { b=bq;  w2=192; lc2=gc;     dst=ws+OFF_Q;  }
        else if (gc < 384) { b=bk;  w2=192; lc2=gc-192; dst=ws+OFF_K;  }
        else if (gc < 576) { b=bv;  w2=192; lc2=gc-384; dst=ws+OFF_V;  }
        else if (gc < 720) { b=bqp; w2=144; lc2=gc-576; dst=ws+OFF_QP; }
        else if (gc < 864) { b=bkp; w2=144; lc2=gc-720; dst=ws+OFF_KP; }
        else               { b=bvp; w2=288; lc2=gc-864; dst=ws+OFF_VP; }
        float4 b4 = *(const float4*)(b + lc2);
        sum.x += b4.x; sum.y += b4.y; sum.z += b4.z; sum.w += b4.w;
        *(float4*)(dst + (size_t)(n0+row)*w2 + lc2) = sum;
    }
}

// ---------------- Kernel 2: global frames + q_sq/k_sq -----------------
__global__ __launch_bounds__(192) void k_frames(
    const float* __restrict__ rot, const float* __restrict__ trans,
    float* __restrict__ ws)
{
    int n = blockIdx.x, tid = threadIdx.x;
    __shared__ float R[9], T[3], qg_s[144], kg_s[144];
    if (tid < 9) R[tid] = rot[n*9 + tid];
    if (tid < 3) T[tid] = trans[n*3 + tid];
    __syncthreads();
    if (tid < 48) {
        const float* lp = ws + OFF_QP + n*144 + tid*3;
        float l0=lp[0], l1=lp[1], l2=lp[2];
        float* gp = ws + OFF_QG + n*144 + tid*3;
        for (int i=0;i<3;i++){ float g = R[i*3+0]*l0 + R[i*3+1]*l1 + R[i*3+2]*l2 + T[i]; gp[i]=g; qg_s[tid*3+i]=g; }
    } else if (tid < 96) {
        int u = tid-48;
        const float* lp = ws + OFF_KP + n*144 + u*3;
        float l0=lp[0], l1=lp[1], l2=lp[2];
        float* gp = ws + OFF_KG + n*144 + u*3;
        for (int i=0;i<3;i++){ float g = R[i*3+0]*l0 + R[i*3+1]*l1 + R[i*3+2]*l2 + T[i]; gp[i]=g; kg_s[u*3+i]=g; }
    } else {
        int u = tid-96;
        const float* lp = ws + OFF_VP + n*288 + u*3;
        float l0=lp[0], l1=lp[1], l2=lp[2];
        float* gp = ws + OFF_VG + n*288 + u*3;
        for (int i=0;i<3;i++){ float g = R[i*3+0]*l0 + R[i*3+1]*l1 + R[i*3+2]*l2 + T[i]; gp[i]=g; }
    }
    __syncthreads();
    if (tid < 12) {
        float a=0;
        for (int d=0; d<12; d++){ float x=qg_s[tid*12+d]; a+=x*x; }
        ws[OFF_QSQ + n*12 + tid]=a;
    } else if (tid < 24) {
        int h = tid-12; float a=0;
        for (int d=0; d<12; d++){ float x=kg_s[h*12+d]; a+=x*x; }
        ws[OFF_KSQ + n*12 + h]=a;
    }
}

// ---------------- Kernel 3: qk + point logits, per-head 64x64 tiles ----------
__global__ __launch_bounds__(256) void k_qkpt(
    const float* __restrict__ head_weights, float* __restrict__ ws)
{
    __shared__ float qs[QKD*QPAD], ks[QKD*QPAD], qa[64], kb[64];
    const int tid = threadIdx.x;
    const int m0 = blockIdx.x * 64, n0 = blockIdx.y * 64, h = blockIdx.z;
    const float hw = head_weights[h];
    for (int idx = tid; idx < 64*16; idx += 256) {
        int r = idx >> 4, c = idx & 15;
        qs[c*QPAD + r] = ws[OFF_Q + (n0+r)*192 + h*16 + c] * 0.25f;
        ks[c*QPAD + r] = ws[OFF_K + (m0+r)*192 + h*16 + c];
    }
    for (int idx = tid; idx < 64*12; idx += 256) {
        int r = idx / 12, c = idx % 12;
        qs[(16+c)*QPAD + r] = ws[OFF_QG + (n0+r)*144 + h*12 + c] * hw;
        ks[(16+c)*QPAD + r] = ws[OFF_KG + (m0+r)*144 + h*12 + c];
    }
    for (int idx = tid; idx < 64; idx += 256) {
        qa[idx] = -0.5f * hw * ws[OFF_QSQ + (n0+idx)*12 + h];
        kb[idx] = -0.5f * hw * ws[OFF_KSQ + (m0+idx)*12 + h];
    }
    __syncthreads();
    const int tx = tid & 15, ty = tid >> 4;
    float acc[4][4] = {{0.f}};
    #pragma unroll 4
    for (int d = 0; d < QKD; d++) {
        float4 a = *(const float4*)(qs + d*QPAD + ty*4);
        float4 b = *(const float4*)(ks + d*QPAD + tx*4);
        const float* ap = &a.x; const float* bp = &b.x;
        #pragma unroll
        for (int i=0;i<4;i++)
            #pragma unroll
            for (int j=0;j<4;j++) acc[i][j] += ap[i]*bp[j];
    }
    #pragma unroll
    for (int i=0;i<4;i++) {
        float ai = qa[ty*4+i];
        float4 r;
        r.x = acc[i][0] + ai + kb[tx*4+0];
        r.y = acc[i][1] + ai + kb[tx*4+1];
        r.z = acc[i][2] + ai + kb[tx*4+2];
        r.w = acc[i][3] + ai + kb[tx*4+3];
        *(float4*)(ws + OFF_LOG + ((size_t)(n0+ty*4+i)*H + h)*N + m0 + tx*4) = r;
    }
}

// ---------------- Kernel 4: FUSED bias + softmax + attn@{z,V,VG} ---------------
// One block per n (512 blocks x 256 thr).
// Phase 1 REWRITTEN: z staged in LDS via coalesced chunks (64 m x 128 c = 32 KB),
// wave w owns c-slice [w*32, w*32+32); LDS reduce of 4 c-partials; bias added.
// Fixes the 512B-stride per-lane z pattern (64 lines/wave-instr -> 16).
__global__ __launch_bounds__(256) void k_attn_all(
    const float* __restrict__ z, const float* __restrict__ trans,
    const float* __restrict__ rot,
    const float* __restrict__ Wb, const float* __restrict__ bb,
    const float* __restrict__ dist_emb, const float* __restrict__ scale_logits,
    float* __restrict__ ws)
{
    __shared__ float attn_s[H*APAD];     // 24.2 KB
    __shared__ float zs[64*ZPAD];        // 33 KB  (aliased as 'part' in ph2/3)
    __shared__ float partial[4*64*13];   // 13 KB  phase-1 c-slice partials
    __shared__ float Wb_s[CZ*12];        // 6 KB
    __shared__ float og_s[288];
    __shared__ float sprob[36];          // [s][h] 3x12 scale-softmax probs
    float* part = zs;                    // phases 2/3 reuse the z-stage buffer
    const int n = blockIdx.x, tid = threadIdx.x;
    const int lane = tid & 63, wave = tid >> 6;

    // ---- once: per-head 3-way softmax of scale_logits; Wb -> LDS ----
    if (tid < 12) {
        float sa = scale_logits[tid], sb = scale_logits[12+tid], sc = scale_logits[24+tid];
        float mx = fmaxf(sa, fmaxf(sb, sc));
        float ea=__expf(sa-mx), eb=__expf(sb-mx), ec=__expf(sc-mx);
        float inv = 1.f/(ea+eb+ec);
        sprob[tid] = ea*inv; sprob[12+tid] = eb*inv; sprob[24+tid] = ec*inv;
    }
    for (int i = tid; i < 384; i += 256)        // 1536 floats of Wb
        *(float4*)(Wb_s + i*4) = *(const float4*)(Wb + i*4);

    // ---- stage raw logits ----
    const float4* asrc = (const float4*)(ws + OFF_LOG + (size_t)n*H*N);
    for (int i = tid; i < H*(N/4); i += 256) {
        int h = i >> 7, q = i & 127;
        *(float4*)(attn_s + h*APAD + q*4) = asrc[h*128 + q];
    }
    __syncthreads();

    // ---- phase 1: bias = z@Wb + bb + dist + multiscale, LDS-staged chunks ----
    {
        const float tnx = trans[n*3+0], tny = trans[n*3+1], tnz = trans[n*3+2];
        const int h0 = wave*3;
        const float bbv0 = bb[h0], bbv1 = bb[h0+1], bbv2 = bb[h0+2];
        const float spc0 = sprob[24+h0], spc1 = sprob[24+h0+1], spc2 = sprob[24+h0+2];
        const float spa0 = sprob[h0],    spa1 = sprob[h0+1],    spa2 = sprob[h0+2];
        const float spb0 = sprob[12+h0], spb1 = sprob[12+h0+1], spb2 = sprob[12+h0+2];
        const float4* zsrc4 = (const float4*)(z + (size_t)n*N*CZ);
        for (int chunk = 0; chunk < 8; chunk++) {
            // coalesced stage: 64 rows x 128 c
            #pragma unroll
            for (int pass = 0; pass < 8; pass++) {
                int idx = pass*256 + tid;                 // float4 idx in chunk
                float4 v = zsrc4[chunk*2048 + idx];
                *(float4*)(zs + (idx>>5)*ZPAD + (idx&31)*4) = v;
            }
            __syncthreads();
            {   // wave = c-slice, lane = m-row
                const float* zrow = zs + lane*ZPAD + wave*32;
                float a[12];
                #pragma unroll
                for (int h=0;h<12;h++) a[h]=0.f;
                #pragma unroll
                for (int c4=0;c4<8;c4++) {
                    float4 zq = *(const float4*)(zrow + c4*4);
                    const float* wr = Wb_s + (wave*32 + c4*4)*12;
                    const float* zp = &zq.x;
                    #pragma unroll
                    for (int j=0;j<4;j++) {
                        float4 w0 = *(const float4*)(wr + j*12);
                        float4 w1 = *(const float4*)(wr + j*12 + 4);
                        float4 w2 = *(const float4*)(wr + j*12 + 8);
                        float zj = zp[j];
                        a[0]+=zj*w0.x; a[1]+=zj*w0.y; a[2]+=zj*w0.z; a[3]+=zj*w0.w;
                        a[4]+=zj*w1.x; a[5]+=zj*w1.y; a[6]+=zj*w1.z; a[7]+=zj*w1.w;
                        a[8]+=zj*w2.x; a[9]+=zj*w2.y; a[10]+=zj*w2.z; a[11]+=zj*w2.w;
                    }
                }
                float* pdst = partial + (wave*64 + lane)*13;
                #pragma unroll
                for (int h=0;h<12;h++) pdst[h] = a[h];
            }
            __syncthreads();
            {   // final: lane = m-row, wave = h-triple; reduce 4 c-slices + bias
                const int m = chunk*64 + lane;
                float dx = tnx - trans[m*3+0];
                float dy = tny - trans[m*3+1];
                float dz = tnz - trans[m*3+2];
                float pdist = sqrtf(dx*dx+dy*dy+dz*dz);
                int bin = (int)ceilf(2.f*pdist) - 1;
                bin = bin < 0 ? 0 : (bin > NB-1 ? NB-1 : bin);
                const int ssel = (pdist <= 5.f) ? 0 : (pdist <= 15.f ? 1 : -1);
                float v0 = partial[(0*64+lane)*13 + h0]   + partial[(1*64+lane)*13 + h0]
                         + partial[(2*64+lane)*13 + h0]   + partial[(3*64+lane)*13 + h0];
                float v1 = partial[(0*64+lane)*13 + h0+1] + partial[(1*64+lane)*13 + h0+1]
                         + partial[(2*64+lane)*13 + h0+1] + partial[(3*64+lane)*13 + h0+1];
                float v2 = partial[(0*64+lane)*13 + h0+2] + partial[(1*64+lane)*13 + h0+2]
                         + partial[(2*64+lane)*13 + h0+2] + partial[(3*64+lane)*13 + h0+2];
                v0 += bbv0 + dist_emb[bin*12 + h0]   + spc0;
                v1 += bbv1 + dist_emb[bin*12 + h0+1] + spc1;
                v2 += bbv2 + dist_emb[bin*12 + h0+2] + spc2;
                if (ssel == 0)      { v0 += spa0; v1 += spa1; v2 += spa2; }
                else if (ssel == 1) { v0 += spb0; v1 += spb1; v2 += spb2; }
                attn_s[(h0  )*APAD + m] += v0;
                attn_s[(h0+1)*APAD + m] += v1;
                attn_s[(h0+2)*APAD + m] += v2;
            }
            __syncthreads();   // protect zs/partial before next chunk stage
        }
    }

    // ---- softmax (wave per h-row), once ----
    for (int h = wave; h < H; h += 4) {
        float* row = attn_s + h*APAD;
        float v[8]; float mx = -1e30f;
        #pragma unroll
        for (int j=0;j<8;j++){ v[j]=row[lane + j*64]; mx = fmaxf(mx, v[j]); }
        #pragma unroll
        for (int off=32; off>0; off>>=1) mx = fmaxf(mx, __shfl_xor(mx, off, 64));
        float sum = 0.f;
        #pragma unroll
        for (int j=0;j<8;j++){ v[j]=__expf(v[j]-mx); sum += v[j]; }
        #pragma unroll
        for (int off=32; off>0; off>>=1) sum += __shfl_xor(sum, off, 64);
        float inv = 1.f/sum;
        #pragma unroll
        for (int j=0;j<8;j++) row[lane + j*64] = v[j]*inv;
    }
    __syncthreads();

    // ---- phase 2: pair_feat = attn @ z (both channel halves) ----
    const int cq = tid & 15;
    const int ms = tid >> 4;
    for (int ch = 0; ch < 2; ch++) {
        const float* zb = z + (size_t)n*N*CZ + ch*64 + cq*4;
        float4 acc[12];
        #pragma unroll
        for (int h=0; h<12; h++) acc[h] = make_float4(0.f,0.f,0.f,0.f);
        const int r0 = ms*32;
        #pragma unroll 2
        for (int rq = 0; rq < 8; rq++) {
            const int r = r0 + rq*4;
            float4 z0 = *(const float4*)(zb + (size_t)(r+0)*CZ);
            float4 z1 = *(const float4*)(zb + (size_t)(r+1)*CZ);
            float4 z2 = *(const float4*)(zb + (size_t)(r+2)*CZ);
            float4 z3 = *(const float4*)(zb + (size_t)(r+3)*CZ);
            #pragma unroll
            for (int h=0; h<12; h++) {
                float4 a4 = *(const float4*)(attn_s + h*APAD + r);
                acc[h].x += a4.x*z0.x + a4.y*z1.x + a4.z*z2.x + a4.w*z3.x;
                acc[h].y += a4.x*z0.y + a4.y*z1.y + a4.z*z2.y + a4.w*z3.y;
                acc[h].z += a4.x*z0.z + a4.y*z1.z + a4.z*z2.z + a4.w*z3.z;
                acc[h].w += a4.x*z0.w + a4.y*z1.w + a4.z*z2.w + a4.w*z3.w;
            }
        }
        #pragma unroll
        for (int h=0; h<12; h++) {
            acc[h].x += __shfl_xor(acc[h].x, 16, 64); acc[h].y += __shfl_xor(acc[h].y, 16, 64);
            acc[h].z += __shfl_xor(acc[h].z, 16, 64); acc[h].w += __shfl_xor(acc[h].w, 16, 64);
            acc[h].x += __shfl_xor(acc[h].x, 32, 64); acc[h].y += __shfl_xor(acc[h].y, 32, 64);
            acc[h].z += __shfl_xor(acc[h].z, 32, 64); acc[h].w += __shfl_xor(acc[h].w, 32, 64);
        }
        if (lane < 16) {
            #pragma unroll
            for (int h=0; h<12; h++)
                *(float4*)(part + (wave*12 + h)*64 + lane*4) = acc[h];
        }
        __syncthreads();
        if (tid < 192) {
            const int h = tid >> 4, c4 = tid & 15;
            float4 s4 = *(const float4*)(part + (0*12 + h)*64 + c4*4);
            #pragma unroll
            for (int w=1; w<4; w++) {
                float4 p = *(const float4*)(part + (w*12 + h)*64 + c4*4);
                s4.x += p.x; s4.y += p.y; s4.z += p.z; s4.w += p.w;
            }
            *(float4*)(ws + OFF_FEAT + (size_t)n*2112 + h*176 + 48 + ch*64 + c4*4) = s4;
        }
        __syncthreads();   // protect part before reuse
    }

    // ---- phase 3: attn @ {V, VG} ----
    if (tid < 240) {
        const int col4 = (tid % 120) * 4;
        const int msA  = tid / 120;
        const float* aptr; int astride, ah;
        if (col4 < 192) { ah = col4 >> 4;        aptr = ws + OFF_V  + col4;       astride = 192; }
        else            { ah = (col4-192) / 24;  aptr = ws + OFF_VG + (col4-192); astride = 288; }
        const float4* arow = (const float4*)(attn_s + ah*APAD);
        float4 acc = {0.f,0.f,0.f,0.f};
        #pragma unroll 2
        for (int mq = msA*64; mq < msA*64 + 64; mq++) {
            float4 a4 = arow[mq];
            const float* vp = aptr + (size_t)mq*4*astride;
            float4 v0 = *(const float4*)(vp);
            float4 v1 = *(const float4*)(vp + astride);
            float4 v2 = *(const float4*)(vp + 2*astride);
            float4 v3 = *(const float4*)(vp + 3*astride);
            acc.x += a4.x*v0.x + a4.y*v1.x + a4.z*v2.x + a4.w*v3.x;
            acc.y += a4.x*v0.y + a4.y*v1.y + a4.z*v2.y + a4.w*v3.y;
            acc.z += a4.x*v0.z + a4.y*v1.z + a4.z*v2.z + a4.w*v3.z;
            acc.w += a4.x*v0.w + a4.y*v1.w + a4.z*v2.w + a4.w*v3.w;
        }
        *(float4*)(part + tid*4) = acc;
    }
    __syncthreads();
    if (tid < 120) {
        const int col4 = tid * 4;
        float4 a = *(const float4*)(part + tid*4);
        float4 b = *(const float4*)(part + (tid+120)*4);
        a.x += b.x; a.y += b.y; a.z += b.z; a.w += b.w;
        if (col4 < 192) {
            const int ah = col4 >> 4;
            *(float4*)(ws + OFF_FEAT + (size_t)n*2112 + ah*176 + (col4 & 15)) = a;
        } else {
            *(float4*)(og_s + (col4 - 192)) = a;
        }
    }
    __syncthreads();
    if (tid < 96) {                              // rotate to local frame + norms
        const int h = tid >> 3, p = tid & 7;
        float g0 = og_s[h*24 + p*3 + 0] - trans[n*3+0];
        float g1 = og_s[h*24 + p*3 + 1] - trans[n*3+1];
        float g2 = og_s[h*24 + p*3 + 2] - trans[n*3+2];
        const float* R = rot + n*9;
        float* fdst = ws + OFF_FEAT + (size_t)n*2112 + h*176;
        float nsq = 0.f;
        #pragma unroll
        for (int i=0;i<3;i++){
            float l = R[0*3+i]*g0 + R[1*3+i]*g1 + R[2*3+i]*g2;   // R^T
            fdst[16 + p*3 + i] = l;
            nsq += l*l;
        }
        fdst[40 + p] = sqrtf(nsq);
    }
}

// ---------------- Kernel 5a: init out with bias -----------------
__global__ __launch_bounds__(384) void k_bias(
    const float* __restrict__ bout, float* __restrict__ out)
{
    out[(size_t)blockIdx.x*CS + threadIdx.x] = bout[threadIdx.x];
}

// ---------------- Kernel 5b: output GEMM (register-tiled), K split 4 ways ------
__global__ __launch_bounds__(256) void k_out(
    const float* __restrict__ Wout, const float* __restrict__ ws,
    float* __restrict__ out)
{
    __shared__ float f_s[16*KSP];        // 33.8 KB
    __shared__ float part[4*16*68];      // 17.4 KB
    const int tid = threadIdx.x;
    const int n0  = blockIdx.y * 16;
    const int k0  = blockIdx.z * KSP;
    const int cq  = tid & 15;
    const int rg  = (tid >> 4) & 3;
    const int ks  = tid >> 6;
    const int col = blockIdx.x * 64 + cq * 4;
    for (int i = tid; i < 16*KSP; i += 256) {
        int r = i / KSP, c = i - r*KSP;
        f_s[i] = ws[OFF_FEAT + (size_t)(n0 + r)*2112 + k0 + c];
    }
    __syncthreads();
    float acc[4][4] = {{0.f}};
    const float* wp = Wout + (size_t)(k0 + ks*132)*CS + col;
    const float* f0 = f_s + (rg*4)*KSP + ks*132;
    #pragma unroll 4
    for (int kk = 0; kk < 132; kk++) {
        float4 w4 = *(const float4*)(wp + (size_t)kk*CS);
        #pragma unroll
        for (int r = 0; r < 4; r++) {
            float fv = f0[r*KSP + kk];
            acc[r][0] += fv*w4.x; acc[r][1] += fv*w4.y;
            acc[r][2] += fv*w4.z; acc[r][3] += fv*w4.w;
        }
    }
    #pragma unroll
    for (int r = 0; r < 4; r++)
        *(float4*)(part + (ks*16 + rg*4 + r)*68 + cq*4) =
            make_float4(acc[r][0], acc[r][1], acc[r][2], acc[r][3]);
    __syncthreads();
    {
        const int row = tid >> 4;
        float4 s = *(const float4*)(part + (0*16 + row)*68 + cq*4);
        #pragma unroll
        for (int k2 = 1; k2 < 4; k2++) {
            float4 p = *(const float4*)(part + (k2*16 + row)*68 + cq*4);
            s.x += p.x; s.y += p.y; s.z += p.z; s.w += p.w;
        }
        float* o = out + (size_t)(n0+row)*CS + col;
        atomicAdd(o+0, s.x); atomicAdd(o+1, s.y);
        atomicAdd(o+2, s.z); atomicAdd(o+3, s.w);
    }
}

extern "C" void kernel_launch(void* const* d_in, const int* in_sizes, int n_in,
                              void* d_out, int out_size, void* d_ws, size_t ws_size,
                              hipStream_t stream) {
    const float* s     = (const float*)d_in[0];
    const float* z     = (const float*)d_in[1];
    const float* trans = (const float*)d_in[2];
    const float* rot   = (const float*)d_in[3];
    const float* Wq  = (const float*)d_in[5];  const float* bq  = (const float*)d_in[6];
    const float* Wk  = (const float*)d_in[7];  const float* bk  = (const float*)d_in[8];
    const float* Wv  = (const float*)d_in[9];  const float* bv  = (const float*)d_in[10];
    const float* Wqp = (const float*)d_in[11]; const float* bqp = (const float*)d_in[12];
    const float* Wkp = (const float*)d_in[13]; const float* bkp = (const float*)d_in[14];
    const float* Wvp = (const float*)d_in[15]; const float* bvp = (const float*)d_in[16];
    const float* Wb  = (const float*)d_in[17]; const float* bb  = (const float*)d_in[18];
    const float* dist_emb     = (const float*)d_in[19];
    const float* scale_logits = (const float*)d_in[20];
    const float* head_weights = (const float*)d_in[21];
    const float* Wout = (const float*)d_in[22]; const float* bout = (const float*)d_in[23];
    float* out = (float*)d_out;
    float* ws  = (float*)d_ws;

    k_proj<<<dim3(18, 32), 256, 0, stream>>>(s, Wq,bq, Wk,bk, Wv,bv, Wqp,bqp, Wkp,bkp, Wvp,bvp, ws);
    k_frames<<<N, 192, 0, stream>>>(rot, trans, ws);
    k_qkpt<<<dim3(8, 8, 12), 256, 0, stream>>>(head_weights, ws);
    k_attn_all<<<N, 256, 0, stream>>>(z, trans, rot, Wb, bb, dist_emb, scale_logits, ws);
    k_bias<<<N, CS, 0, stream>>>(bout, out);
    k_out<<<dim3(6, 32, 4), 256, 0, stream>>>(Wout, ws, out);
}

// Round 8
// 343.843 us; speedup vs baseline: 1.0612x; 1.0612x over previous
//
#include <hip/hip_runtime.h>
#include <math.h>

#define N   512
#define CS  384
#define CZ  128
#define H   12
#define C   16
#define P   4
#define PV  8
#define NB  64
#define KSP 528   // K-slice for k_out (2112/4)
#define QKD 28    // 16 (q·k) + 12 (qg·kg) fused dot length
#define QPAD 68   // d-major LDS row stride (k_qkpt)
#define APAD 516  // attn LDS row stride
#define ZP2 132   // z-chunk LDS row stride (k_zbias2)

// workspace offsets (in floats)
#define OFF_Q    0         // 512*192
#define OFF_K    98304     // 512*192
#define OFF_V    196608    // 512*192
#define OFF_QP   294912    // 512*144
#define OFF_KP   368640    // 512*144
#define OFF_VP   442368    // 512*288
#define OFF_QG   589824    // 512*144
#define OFF_KG   663552    // 512*144
#define OFF_VG   737280    // 512*288
#define OFF_QSQ  884736    // 512*12
#define OFF_KSQ  890880    // 512*12
#define OFF_LOG  897024    // 512*12*512  (logits -> biased -> normalized attn)
#define OFF_FEAT 4042752   // 512*2112

// ---------------- Kernel 1: all six projections (register-tiled GEMM) ----------
__global__ __launch_bounds__(256) void k_proj(
    const float* __restrict__ s,
    const float* __restrict__ Wq,  const float* __restrict__ bq,
    const float* __restrict__ Wk,  const float* __restrict__ bk,
    const float* __restrict__ Wv,  const float* __restrict__ bv,
    const float* __restrict__ Wqp, const float* __restrict__ bqp,
    const float* __restrict__ Wkp, const float* __restrict__ bkp,
    const float* __restrict__ Wvp, const float* __restrict__ bvp,
    float* __restrict__ ws)
{
    __shared__ float s_s[16*388];        // 24.8 KB
    __shared__ float part[4*16*68];      // 17.4 KB  (ks, row, col64 padded)
    const int tid = threadIdx.x;
    const int n0  = blockIdx.y * 16;
    const int cq  = tid & 15;
    const int rg  = (tid >> 4) & 3;
    const int ks  = tid >> 6;
    const int gc  = blockIdx.x * 64 + cq * 4;
    for (int i = tid; i < 16*384; i += 256) {
        int r = i / 384, c = i - r*384;
        s_s[r*388 + c] = s[(n0 + r)*384 + c];
    }
    __syncthreads();
    const float* W; int width; int lc;
    if      (gc < 192) { W=Wq;  width=192; lc=gc;     }
    else if (gc < 384) { W=Wk;  width=192; lc=gc-192; }
    else if (gc < 576) { W=Wv;  width=192; lc=gc-384; }
    else if (gc < 720) { W=Wqp; width=144; lc=gc-576; }
    else if (gc < 864) { W=Wkp; width=144; lc=gc-720; }
    else               { W=Wvp; width=288; lc=gc-864; }
    float acc[4][4] = {{0.f}};
    const float* wp   = W + lc + (size_t)(ks*96)*width;
    const float* srow = s_s + (rg*4)*388 + ks*96;
    #pragma unroll 4
    for (int kk = 0; kk < 96; kk++) {
        float4 w4 = *(const float4*)(wp + (size_t)kk*width);
        #pragma unroll
        for (int r = 0; r < 4; r++) {
            float sv = srow[r*388 + kk];
            acc[r][0] += sv*w4.x; acc[r][1] += sv*w4.y;
            acc[r][2] += sv*w4.z; acc[r][3] += sv*w4.w;
        }
    }
    #pragma unroll
    for (int r = 0; r < 4; r++)
        *(float4*)(part + (ks*16 + rg*4 + r)*68 + cq*4) =
            make_float4(acc[r][0], acc[r][1], acc[r][2], acc[r][3]);
    __syncthreads();
    {   // 256 threads: (row = tid>>4, same cq) sum 4 K-partials + bias, store
        const int row = tid >> 4;
        float4 sum = *(const float4*)(part + (0*16 + row)*68 + cq*4);
        #pragma unroll
        for (int k2 = 1; k2 < 4; k2++) {
            float4 p = *(const float4*)(part + (k2*16 + row)*68 + cq*4);
            sum.x += p.x; sum.y += p.y; sum.z += p.z; sum.w += p.w;
        }
        const float* b; float* dst; int w2, lc2;
        if      (gc < 192) { b=bq;  w2=192; lc2=gc;     dst=ws+OFF_Q;  }
        else if (gc < 384) { b=bk;  w2=192; lc2=gc-192; dst=ws+OFF_K;  }
        else if (gc < 576) { b=bv;  w2=192; lc2=gc-384; dst=ws+OFF_V;  }
        else if (gc < 720) { b=bqp; w2=144; lc2=gc-576; dst=ws+OFF_QP; }
        else if (gc < 864) { b=bkp; w2=144; lc2=gc-720; dst=ws+OFF_KP; }
        else               { b=bvp; w2=288; lc2=gc-864; dst=ws+OFF_VP; }
        float4 b4 = *(const float4*)(b + lc2);
        sum.x += b4.x; sum.y += b4.y; sum.z += b4.z; sum.w += b4.w;
        *(float4*)(dst + (size_t)(n0+row)*w2 + lc2) = sum;
    }
}

// ---------------- Kernel 2: global frames + q_sq/k_sq -----------------
__global__ __launch_bounds__(192) void k_frames(
    const float* __restrict__ rot, const float* __restrict__ trans,
    float* __restrict__ ws)
{
    int n = blockIdx.x, tid = threadIdx.x;
    __shared__ float R[9], T[3], qg_s[144], kg_s[144];
    if (tid < 9) R[tid] = rot[n*9 + tid];
    if (tid < 3) T[tid] = trans[n*3 + tid];
    __syncthreads();
    if (tid < 48) {
        const float* lp = ws + OFF_QP + n*144 + tid*3;
        float l0=lp[0], l1=lp[1], l2=lp[2];
        float* gp = ws + OFF_QG + n*144 + tid*3;
        for (int i=0;i<3;i++){ float g = R[i*3+0]*l0 + R[i*3+1]*l1 + R[i*3+2]*l2 + T[i]; gp[i]=g; qg_s[tid*3+i]=g; }
    } else if (tid < 96) {
        int u = tid-48;
        const float* lp = ws + OFF_KP + n*144 + u*3;
        float l0=lp[0], l1=lp[1], l2=lp[2];
        float* gp = ws + OFF_KG + n*144 + u*3;
        for (int i=0;i<3;i++){ float g = R[i*3+0]*l0 + R[i*3+1]*l1 + R[i*3+2]*l2 + T[i]; gp[i]=g; kg_s[u*3+i]=g; }
    } else {
        int u = tid-96;
        const float* lp = ws + OFF_VP + n*288 + u*3;
        float l0=lp[0], l1=lp[1], l2=lp[2];
        float* gp = ws + OFF_VG + n*288 + u*3;
        for (int i=0;i<3;i++){ float g = R[i*3+0]*l0 + R[i*3+1]*l1 + R[i*3+2]*l2 + T[i]; gp[i]=g; }
    }
    __syncthreads();
    if (tid < 12) {
        float a=0;
        for (int d=0; d<12; d++){ float x=qg_s[tid*12+d]; a+=x*x; }
        ws[OFF_QSQ + n*12 + tid]=a;
    } else if (tid < 24) {
        int h = tid-12; float a=0;
        for (int d=0; d<12; d++){ float x=kg_s[h*12+d]; a+=x*x; }
        ws[OFF_KSQ + n*12 + h]=a;
    }
}

// ---------------- Kernel 3: qk + point logits, per-head 64x64 tiles ----------
__global__ __launch_bounds__(256) void k_qkpt(
    const float* __restrict__ head_weights, float* __restrict__ ws)
{
    __shared__ float qs[QKD*QPAD], ks[QKD*QPAD], qa[64], kb[64];
    const int tid = threadIdx.x;
    const int m0 = blockIdx.x * 64, n0 = blockIdx.y * 64, h = blockIdx.z;
    const float hw = head_weights[h];
    for (int idx = tid; idx < 64*16; idx += 256) {
        int r = idx >> 4, c = idx & 15;
        qs[c*QPAD + r] = ws[OFF_Q + (n0+r)*192 + h*16 + c] * 0.25f;
        ks[c*QPAD + r] = ws[OFF_K + (m0+r)*192 + h*16 + c];
    }
    for (int idx = tid; idx < 64*12; idx += 256) {
        int r = idx / 12, c = idx % 12;
        qs[(16+c)*QPAD + r] = ws[OFF_QG + (n0+r)*144 + h*12 + c] * hw;
        ks[(16+c)*QPAD + r] = ws[OFF_KG + (m0+r)*144 + h*12 + c];
    }
    for (int idx = tid; idx < 64; idx += 256) {
        qa[idx] = -0.5f * hw * ws[OFF_QSQ + (n0+idx)*12 + h];
        kb[idx] = -0.5f * hw * ws[OFF_KSQ + (m0+idx)*12 + h];
    }
    __syncthreads();
    const int tx = tid & 15, ty = tid >> 4;
    float acc[4][4] = {{0.f}};
    #pragma unroll 4
    for (int d = 0; d < QKD; d++) {
        float4 a = *(const float4*)(qs + d*QPAD + ty*4);
        float4 b = *(const float4*)(ks + d*QPAD + tx*4);
        const float* ap = &a.x; const float* bp = &b.x;
        #pragma unroll
        for (int i=0;i<4;i++)
            #pragma unroll
            for (int j=0;j<4;j++) acc[i][j] += ap[i]*bp[j];
    }
    #pragma unroll
    for (int i=0;i<4;i++) {
        float ai = qa[ty*4+i];
        float4 r;
        r.x = acc[i][0] + ai + kb[tx*4+0];
        r.y = acc[i][1] + ai + kb[tx*4+1];
        r.z = acc[i][2] + ai + kb[tx*4+2];
        r.w = acc[i][3] + ai + kb[tx*4+3];
        *(float4*)(ws + OFF_LOG + ((size_t)(n0+ty*4+i)*H + h)*N + m0 + tx*4) = r;
    }
}

// ---------------- Kernel 4a: z@Wb + bb + dist + multiscale -> LOG (RMW) --------
// grid (4 mb, 512 n) x 256 thr = 2048 blocks. Per block: 128 m-rows in 2 chunks
// of 64. LDS-staged z (coalesced), wave = c-slice, lane = m-row (conflict-free).
// LDS 53 KB -> 3 blocks/CU.
__global__ __launch_bounds__(256) void k_zbias2(
    const float* __restrict__ z, const float* __restrict__ trans,
    const float* __restrict__ Wb, const float* __restrict__ bb,
    const float* __restrict__ dist_emb, const float* __restrict__ scale_logits,
    float* __restrict__ ws)
{
    __shared__ float zs[64*ZP2];         // 33.8 KB
    __shared__ float partial[4*64*13];   // 13.3 KB
    __shared__ float Wb_s[CZ*12];        // 6 KB
    __shared__ float sprob[36];
    const int mb = blockIdx.x, n = blockIdx.y;
    const int tid = threadIdx.x, lane = tid & 63, wave = tid >> 6;

    if (tid < 12) {
        float sa = scale_logits[tid], sb = scale_logits[12+tid], sc = scale_logits[24+tid];
        float mx = fmaxf(sa, fmaxf(sb, sc));
        float ea=__expf(sa-mx), eb=__expf(sb-mx), ec=__expf(sc-mx);
        float inv = 1.f/(ea+eb+ec);
        sprob[tid] = ea*inv; sprob[12+tid] = eb*inv; sprob[24+tid] = ec*inv;
    }
    for (int i = tid; i < 384; i += 256)
        *(float4*)(Wb_s + i*4) = *(const float4*)(Wb + i*4);
    __syncthreads();

    const float tnx = trans[n*3+0], tny = trans[n*3+1], tnz = trans[n*3+2];
    const int h0 = wave*3;

    for (int chunk = 0; chunk < 2; chunk++) {
        const int m0 = mb*128 + chunk*64;
        // ---- coalesced stage: 64 rows x 128 c ----
        const float4* zsrc4 = (const float4*)(z + ((size_t)n*N + m0)*CZ);
        #pragma unroll
        for (int p = 0; p < 8; p++) {
            int idx = p*256 + tid;               // float4 index within chunk
            float4 v = zsrc4[idx];
            *(float4*)(zs + (idx>>5)*ZP2 + (idx&31)*4) = v;
        }
        __syncthreads();
        // ---- compute: wave = c-slice [wave*32,+32), lane = m-row ----
        {
            const float* zrow = zs + lane*ZP2 + wave*32;
            float a[12];
            #pragma unroll
            for (int h=0;h<12;h++) a[h]=0.f;
            #pragma unroll
            for (int c4=0;c4<8;c4++) {
                float4 zq = *(const float4*)(zrow + c4*4);
                const float* wr = Wb_s + (wave*32 + c4*4)*12;
                const float* zp = &zq.x;
                #pragma unroll
                for (int j=0;j<4;j++) {
                    float4 w0 = *(const float4*)(wr + j*12);
                    float4 w1 = *(const float4*)(wr + j*12 + 4);
                    float4 w2 = *(const float4*)(wr + j*12 + 8);
                    float zj = zp[j];
                    a[0]+=zj*w0.x; a[1]+=zj*w0.y; a[2]+=zj*w0.z; a[3]+=zj*w0.w;
                    a[4]+=zj*w1.x; a[5]+=zj*w1.y; a[6]+=zj*w1.z; a[7]+=zj*w1.w;
                    a[8]+=zj*w2.x; a[9]+=zj*w2.y; a[10]+=zj*w2.z; a[11]+=zj*w2.w;
                }
            }
            float* pdst = partial + (wave*64 + lane)*13;
            #pragma unroll
            for (int h=0;h<12;h++) pdst[h] = a[h];
        }
        __syncthreads();
        // ---- reduce 4 c-slices + bias terms, RMW into LOG (coalesced) ----
        {
            const int m = m0 + lane;
            float dx = tnx - trans[m*3+0];
            float dy = tny - trans[m*3+1];
            float dz = tnz - trans[m*3+2];
            float pdist = sqrtf(dx*dx+dy*dy+dz*dz);
            int bin = (int)ceilf(2.f*pdist) - 1;
            bin = bin < 0 ? 0 : (bin > NB-1 ? NB-1 : bin);
            const int ssel = (pdist <= 5.f) ? 0 : (pdist <= 15.f ? 1 : -1);
            float v0 = partial[(0*64+lane)*13 + h0]   + partial[(1*64+lane)*13 + h0]
                     + partial[(2*64+lane)*13 + h0]   + partial[(3*64+lane)*13 + h0];
            float v1 = partial[(0*64+lane)*13 + h0+1] + partial[(1*64+lane)*13 + h0+1]
                     + partial[(2*64+lane)*13 + h0+1] + partial[(3*64+lane)*13 + h0+1];
            float v2 = partial[(0*64+lane)*13 + h0+2] + partial[(1*64+lane)*13 + h0+2]
                     + partial[(2*64+lane)*13 + h0+2] + partial[(3*64+lane)*13 + h0+2];
            v0 += bb[h0]   + dist_emb[bin*12 + h0]   + sprob[24+h0];
            v1 += bb[h0+1] + dist_emb[bin*12 + h0+1] + sprob[24+h0+1];
            v2 += bb[h0+2] + dist_emb[bin*12 + h0+2] + sprob[24+h0+2];
            if (ssel == 0)      { v0 += sprob[h0];    v1 += sprob[h0+1];    v2 += sprob[h0+2]; }
            else if (ssel == 1) { v0 += sprob[12+h0]; v1 += sprob[12+h0+1]; v2 += sprob[12+h0+2]; }
            float* lp = ws + OFF_LOG + ((size_t)n*H + h0)*N + m;
            lp[0]   += v0;
            lp[N]   += v1;
            lp[2*N] += v2;
        }
        __syncthreads();   // protect zs/partial before next chunk
    }
}

// ---------------- Kernel 4b: in-place softmax over LOG rows -------------------
// 512 blocks x 256 thr; wave per h-row (3 rows/wave), register-resident.
__global__ __launch_bounds__(256) void k_sm(float* __restrict__ ws)
{
    const int n = blockIdx.x, tid = threadIdx.x;
    const int lane = tid & 63, wave = tid >> 6;
    for (int h = wave; h < H; h += 4) {
        float* row = ws + OFF_LOG + ((size_t)n*H + h)*N;
        float4 a = *(const float4*)(row + lane*8);
        float4 b = *(const float4*)(row + lane*8 + 4);
        float mx = fmaxf(fmaxf(fmaxf(a.x,a.y),fmaxf(a.z,a.w)),
                         fmaxf(fmaxf(b.x,b.y),fmaxf(b.z,b.w)));
        #pragma unroll
        for (int off=32; off>0; off>>=1) mx = fmaxf(mx, __shfl_xor(mx, off, 64));
        a.x=__expf(a.x-mx); a.y=__expf(a.y-mx); a.z=__expf(a.z-mx); a.w=__expf(a.w-mx);
        b.x=__expf(b.x-mx); b.y=__expf(b.y-mx); b.z=__expf(b.z-mx); b.w=__expf(b.w-mx);
        float sum = a.x+a.y+a.z+a.w+b.x+b.y+b.z+b.w;
        #pragma unroll
        for (int off=32; off>0; off>>=1) sum += __shfl_xor(sum, off, 64);
        float inv = 1.f/sum;
        a.x*=inv; a.y*=inv; a.z*=inv; a.w*=inv;
        b.x*=inv; b.y*=inv; b.z*=inv; b.w*=inv;
        *(float4*)(row + lane*8)     = a;
        *(float4*)(row + lane*8 + 4) = b;
    }
}

// ---------------- Kernel 4c: role-split attn@z (role 0) / attn@{V,VG} (role 1) -
__global__ __launch_bounds__(256) void k_attnmm(
    const float* __restrict__ z, const float* __restrict__ trans,
    const float* __restrict__ rot, float* __restrict__ ws)
{
    __shared__ float attn_s[H*APAD];     // 24.2 KB
    __shared__ float part[4*12*64];      // 12 KB
    __shared__ float og_s[288];
    const int n = blockIdx.x, role = blockIdx.y, tid = threadIdx.x;
    const int lane = tid & 63, wave = tid >> 6;

    const float4* asrc = (const float4*)(ws + OFF_LOG + (size_t)n*H*N);
    for (int i = tid; i < H*(N/4); i += 256) {
        int h = i >> 7, q = i & 127;
        *(float4*)(attn_s + h*APAD + q*4) = asrc[h*128 + q];
    }
    __syncthreads();

    if (role == 0) {
        const int cq = tid & 15;
        const int ms = tid >> 4;
        for (int ch = 0; ch < 2; ch++) {
            const float* zb = z + (size_t)n*N*CZ + ch*64 + cq*4;
            float4 acc[12];
            #pragma unroll
            for (int h=0; h<12; h++) acc[h] = make_float4(0.f,0.f,0.f,0.f);
            const int r0 = ms*32;
            #pragma unroll 2
            for (int rq = 0; rq < 8; rq++) {
                const int r = r0 + rq*4;
                float4 z0 = *(const float4*)(zb + (size_t)(r+0)*CZ);
                float4 z1 = *(const float4*)(zb + (size_t)(r+1)*CZ);
                float4 z2 = *(const float4*)(zb + (size_t)(r+2)*CZ);
                float4 z3 = *(const float4*)(zb + (size_t)(r+3)*CZ);
                #pragma unroll
                for (int h=0; h<12; h++) {
                    float4 a4 = *(const float4*)(attn_s + h*APAD + r);
                    acc[h].x += a4.x*z0.x + a4.y*z1.x + a4.z*z2.x + a4.w*z3.x;
                    acc[h].y += a4.x*z0.y + a4.y*z1.y + a4.z*z2.y + a4.w*z3.y;
                    acc[h].z += a4.x*z0.z + a4.y*z1.z + a4.z*z2.z + a4.w*z3.z;
                    acc[h].w += a4.x*z0.w + a4.y*z1.w + a4.z*z2.w + a4.w*z3.w;
                }
            }
            #pragma unroll
            for (int h=0; h<12; h++) {
                acc[h].x += __shfl_xor(acc[h].x, 16, 64); acc[h].y += __shfl_xor(acc[h].y, 16, 64);
                acc[h].z += __shfl_xor(acc[h].z, 16, 64); acc[h].w += __shfl_xor(acc[h].w, 16, 64);
                acc[h].x += __shfl_xor(acc[h].x, 32, 64); acc[h].y += __shfl_xor(acc[h].y, 32, 64);
                acc[h].z += __shfl_xor(acc[h].z, 32, 64); acc[h].w += __shfl_xor(acc[h].w, 32, 64);
            }
            if (lane < 16) {
                #pragma unroll
                for (int h=0; h<12; h++)
                    *(float4*)(part + (wave*12 + h)*64 + lane*4) = acc[h];
            }
            __syncthreads();
            if (tid < 192) {
                const int h = tid >> 4, c4 = tid & 15;
                float4 s4 = *(const float4*)(part + (0*12 + h)*64 + c4*4);
                #pragma unroll
                for (int w=1; w<4; w++) {
                    float4 p = *(const float4*)(part + (w*12 + h)*64 + c4*4);
                    s4.x += p.x; s4.y += p.y; s4.z += p.z; s4.w += p.w;
                }
                *(float4*)(ws + OFF_FEAT + (size_t)n*2112 + h*176 + 48 + ch*64 + c4*4) = s4;
            }
            __syncthreads();
        }
    } else {
        if (tid < 240) {
            const int col4 = (tid % 120) * 4;
            const int msA  = tid / 120;
            const float* aptr; int astride, ah;
            if (col4 < 192) { ah = col4 >> 4;        aptr = ws + OFF_V  + col4;       astride = 192; }
            else            { ah = (col4-192) / 24;  aptr = ws + OFF_VG + (col4-192); astride = 288; }
            const float4* arow = (const float4*)(attn_s + ah*APAD);
            float4 acc = {0.f,0.f,0.f,0.f};
            #pragma unroll 2
            for (int mq = msA*64; mq < msA*64 + 64; mq++) {
                float4 a4 = arow[mq];
                const float* vp = aptr + (size_t)mq*4*astride;
                float4 v0 = *(const float4*)(vp);
                float4 v1 = *(const float4*)(vp + astride);
                float4 v2 = *(const float4*)(vp + 2*astride);
                float4 v3 = *(const float4*)(vp + 3*astride);
                acc.x += a4.x*v0.x + a4.y*v1.x + a4.z*v2.x + a4.w*v3.x;
                acc.y += a4.x*v0.y + a4.y*v1.y + a4.z*v2.y + a4.w*v3.y;
                acc.z += a4.x*v0.z + a4.y*v1.z + a4.z*v2.z + a4.w*v3.z;
                acc.w += a4.x*v0.w + a4.y*v1.w + a4.z*v2.w + a4.w*v3.w;
            }
            *(float4*)(part + tid*4) = acc;
        }
        __syncthreads();
        if (tid < 120) {
            const int col4 = tid * 4;
            float4 a = *(const float4*)(part + tid*4);
            float4 b = *(const float4*)(part + (tid+120)*4);
            a.x += b.x; a.y += b.y; a.z += b.z; a.w += b.w;
            if (col4 < 192) {
                const int ah = col4 >> 4;
                *(float4*)(ws + OFF_FEAT + (size_t)n*2112 + ah*176 + (col4 & 15)) = a;
            } else {
                *(float4*)(og_s + (col4 - 192)) = a;
            }
        }
        __syncthreads();
        if (tid < 96) {                          // rotate to local frame + norms
            const int h = tid >> 3, p = tid & 7;
            float g0 = og_s[h*24 + p*3 + 0] - trans[n*3+0];
            float g1 = og_s[h*24 + p*3 + 1] - trans[n*3+1];
            float g2 = og_s[h*24 + p*3 + 2] - trans[n*3+2];
            const float* R = rot + n*9;
            float* fdst = ws + OFF_FEAT + (size_t)n*2112 + h*176;
            float nsq = 0.f;
            #pragma unroll
            for (int i=0;i<3;i++){
                float l = R[0*3+i]*g0 + R[1*3+i]*g1 + R[2*3+i]*g2;   // R^T
                fdst[16 + p*3 + i] = l;
                nsq += l*l;
            }
            fdst[40 + p] = sqrtf(nsq);
        }
    }
}

// ---------------- Kernel 5a: init out with bias -----------------
__global__ __launch_bounds__(384) void k_bias(
    const float* __restrict__ bout, float* __restrict__ out)
{
    out[(size_t)blockIdx.x*CS + threadIdx.x] = bout[threadIdx.x];
}

// ---------------- Kernel 5b: output GEMM (register-tiled), K split 4 ways ------
__global__ __launch_bounds__(256) void k_out(
    const float* __restrict__ Wout, const float* __restrict__ ws,
    float* __restrict__ out)
{
    __shared__ float f_s[16*KSP];        // 33.8 KB
    __shared__ float part[4*16*68];      // 17.4 KB
    const int tid = threadIdx.x;
    const int n0  = blockIdx.y * 16;
    const int k0  = blockIdx.z * KSP;
    const int cq  = tid & 15;
    const int rg  = (tid >> 4) & 3;
    const int ks  = tid >> 6;
    const int col = blockIdx.x * 64 + cq * 4;
    for (int i = tid; i < 16*KSP; i += 256) {
        int r = i / KSP, c = i - r*KSP;
        f_s[i] = ws[OFF_FEAT + (size_t)(n0 + r)*2112 + k0 + c];
    }
    __syncthreads();
    float acc[4][4] = {{0.f}};
    const float* wp = Wout + (size_t)(k0 + ks*132)*CS + col;
    const float* f0 = f_s + (rg*4)*KSP + ks*132;
    #pragma unroll 4
    for (int kk = 0; kk < 132; kk++) {
        float4 w4 = *(const float4*)(wp + (size_t)kk*CS);
        #pragma unroll
        for (int r = 0; r < 4; r++) {
            float fv = f0[r*KSP + kk];
            acc[r][0] += fv*w4.x; acc[r][1] += fv*w4.y;
            acc[r][2] += fv*w4.z; acc[r][3] += fv*w4.w;
        }
    }
    #pragma unroll
    for (int r = 0; r < 4; r++)
        *(float4*)(part + (ks*16 + rg*4 + r)*68 + cq*4) =
            make_float4(acc[r][0], acc[r][1], acc[r][2], acc[r][3]);
    __syncthreads();
    {
        const int row = tid >> 4;
        float4 s = *(const float4*)(part + (0*16 + row)*68 + cq*4);
        #pragma unroll
        for (int k2 = 1; k2 < 4; k2++) {
            float4 p = *(const float4*)(part + (k2*16 + row)*68 + cq*4);
            s.x += p.x; s.y += p.y; s.z += p.z; s.w += p.w;
        }
        float* o = out + (size_t)(n0+row)*CS + col;
        atomicAdd(o+0, s.x); atomicAdd(o+1, s.y);
        atomicAdd(o+2, s.z); atomicAdd(o+3, s.w);
    }
}

extern "C" void kernel_launch(void* const* d_in, const int* in_sizes, int n_in,
                              void* d_out, int out_size, void* d_ws, size_t ws_size,
                              hipStream_t stream) {
    const float* s     = (const float*)d_in[0];
    const float* z     = (const float*)d_in[1];
    const float* trans = (const float*)d_in[2];
    const float* rot   = (const float*)d_in[3];
    const float* Wq  = (const float*)d_in[5];  const float* bq  = (const float*)d_in[6];
    const float* Wk  = (const float*)d_in[7];  const float* bk  = (const float*)d_in[8];
    const float* Wv  = (const float*)d_in[9];  const float* bv  = (const float*)d_in[10];
    const float* Wqp = (const float*)d_in[11]; const float* bqp = (const float*)d_in[12];
    const float* Wkp = (const float*)d_in[13]; const float* bkp = (const float*)d_in[14];
    const float* Wvp = (const float*)d_in[15]; const float* bvp = (const float*)d_in[16];
    const float* Wb  = (const float*)d_in[17]; const float* bb  = (const float*)d_in[18];
    const float* dist_emb     = (const float*)d_in[19];
    const float* scale_logits = (const float*)d_in[20];
    const float* head_weights = (const float*)d_in[21];
    const float* Wout = (const float*)d_in[22]; const float* bout = (const float*)d_in[23];
    float* out = (float*)d_out;
    float* ws  = (float*)d_ws;

    k_proj<<<dim3(18, 32), 256, 0, stream>>>(s, Wq,bq, Wk,bk, Wv,bv, Wqp,bqp, Wkp,bkp, Wvp,bvp, ws);
    k_frames<<<N, 192, 0, stream>>>(rot, trans, ws);
    k_qkpt<<<dim3(8, 8, 12), 256, 0, stream>>>(head_weights, ws);
    k_zbias2<<<dim3(4, N), 256, 0, stream>>>(z, trans, Wb, bb, dist_emb, scale_logits, ws);
    k_sm<<<N, 256, 0, stream>>>(ws);
    k_attnmm<<<dim3(N, 2), 256, 0, stream>>>(z, trans, rot, ws);
    k_bias<<<N, CS, 0, stream>>>(bout, out);
    k_out<<<dim3(6, 32, 4), 256, 0, stream>>>(Wout, ws, out);
}

// Round 9
// 338.717 us; speedup vs baseline: 1.0773x; 1.0151x over previous
//
#include <hip/hip_runtime.h>
#include <math.h>

#define N   512
#define CS  384
#define CZ  128
#define H   12
#define C   16
#define P   4
#define PV  8
#define NB  64
#define KSP 528   // K-slice for k_out (2112/4)
#define QKD 28    // 16 (q·k) + 12 (qg·kg) fused dot length
#define QPAD 68   // d-major LDS row stride (k_qkpt)
#define APAD 516  // attn LDS row stride
#define ZP2 132   // z-chunk LDS row stride (k_zbias2)

// workspace offsets (in floats)
#define OFF_Q    0         // 512*192
#define OFF_K    98304     // 512*192
#define OFF_V    196608    // 512*192
#define OFF_QP   294912    // 512*144
#define OFF_KP   368640    // 512*144
#define OFF_VP   442368    // 512*288
#define OFF_QG   589824    // 512*144
#define OFF_KG   663552    // 512*144
#define OFF_VG   737280    // 512*288
#define OFF_QSQ  884736    // 512*12
#define OFF_KSQ  890880    // 512*12
#define OFF_LOG  897024    // 512*12*512  (raw logits + z-bias; softmax in consumers)
#define OFF_FEAT 4042752   // 512*2112

// ---------------- Kernel 1: all six projections (register-tiled GEMM) ----------
__global__ __launch_bounds__(256) void k_proj(
    const float* __restrict__ s,
    const float* __restrict__ Wq,  const float* __restrict__ bq,
    const float* __restrict__ Wk,  const float* __restrict__ bk,
    const float* __restrict__ Wv,  const float* __restrict__ bv,
    const float* __restrict__ Wqp, const float* __restrict__ bqp,
    const float* __restrict__ Wkp, const float* __restrict__ bkp,
    const float* __restrict__ Wvp, const float* __restrict__ bvp,
    float* __restrict__ ws)
{
    __shared__ float s_s[16*388];        // 24.8 KB
    __shared__ float part[4*16*68];      // 17.4 KB  (ks, row, col64 padded)
    const int tid = threadIdx.x;
    const int n0  = blockIdx.y * 16;
    const int cq  = tid & 15;
    const int rg  = (tid >> 4) & 3;
    const int ks  = tid >> 6;
    const int gc  = blockIdx.x * 64 + cq * 4;
    for (int i = tid; i < 16*384; i += 256) {
        int r = i / 384, c = i - r*384;
        s_s[r*388 + c] = s[(n0 + r)*384 + c];
    }
    __syncthreads();
    const float* W; int width; int lc;
    if      (gc < 192) { W=Wq;  width=192; lc=gc;     }
    else if (gc < 384) { W=Wk;  width=192; lc=gc-192; }
    else if (gc < 576) { W=Wv;  width=192; lc=gc-384; }
    else if (gc < 720) { W=Wqp; width=144; lc=gc-576; }
    else if (gc < 864) { W=Wkp; width=144; lc=gc-720; }
    else               { W=Wvp; width=288; lc=gc-864; }
    float acc[4][4] = {{0.f}};
    const float* wp   = W + lc + (size_t)(ks*96)*width;
    const float* srow = s_s + (rg*4)*388 + ks*96;
    #pragma unroll 4
    for (int kk = 0; kk < 96; kk++) {
        float4 w4 = *(const float4*)(wp + (size_t)kk*width);
        #pragma unroll
        for (int r = 0; r < 4; r++) {
            float sv = srow[r*388 + kk];
            acc[r][0] += sv*w4.x; acc[r][1] += sv*w4.y;
            acc[r][2] += sv*w4.z; acc[r][3] += sv*w4.w;
        }
    }
    #pragma unroll
    for (int r = 0; r < 4; r++)
        *(float4*)(part + (ks*16 + rg*4 + r)*68 + cq*4) =
            make_float4(acc[r][0], acc[r][1], acc[r][2], acc[r][3]);
    __syncthreads();
    {   // 256 threads: (row = tid>>4, same cq) sum 4 K-partials + bias, store
        const int row = tid >> 4;
        float4 sum = *(const float4*)(part + (0*16 + row)*68 + cq*4);
        #pragma unroll
        for (int k2 = 1; k2 < 4; k2++) {
            float4 p = *(const float4*)(part + (k2*16 + row)*68 + cq*4);
            sum.x += p.x; sum.y += p.y; sum.z += p.z; sum.w += p.w;
        }
        const float* b; float* dst; int w2, lc2;
        if      (gc < 192) { b=bq;  w2=192; lc2=gc;     dst=ws+OFF_Q;  }
        else if (gc < 384) { b=bk;  w2=192; lc2=gc-192; dst=ws+OFF_K;  }
        else if (gc < 576) { b=bv;  w2=192; lc2=gc-384; dst=ws+OFF_V;  }
        else if (gc < 720) { b=bqp; w2=144; lc2=gc-576; dst=ws+OFF_QP; }
        else if (gc < 864) { b=bkp; w2=144; lc2=gc-720; dst=ws+OFF_KP; }
        else               { b=bvp; w2=288; lc2=gc-864; dst=ws+OFF_VP; }
        float4 b4 = *(const float4*)(b + lc2);
        sum.x += b4.x; sum.y += b4.y; sum.z += b4.z; sum.w += b4.w;
        *(float4*)(dst + (size_t)(n0+row)*w2 + lc2) = sum;
    }
}

// ---------------- Kernel 2: global frames + q_sq/k_sq + out-bias init ---------
__global__ __launch_bounds__(192) void k_frames(
    const float* __restrict__ rot, const float* __restrict__ trans,
    const float* __restrict__ bout, float* __restrict__ out,
    float* __restrict__ ws)
{
    int n = blockIdx.x, tid = threadIdx.x;
    __shared__ float R[9], T[3], qg_s[144], kg_s[144];
    if (tid < 9) R[tid] = rot[n*9 + tid];
    if (tid < 3) T[tid] = trans[n*3 + tid];
    // out init with bias (replaces k_bias kernel): 2 rows of 192 each
    out[(size_t)n*CS + tid]       = bout[tid];
    out[(size_t)n*CS + 192 + tid] = bout[192 + tid];
    __syncthreads();
    if (tid < 48) {
        const float* lp = ws + OFF_QP + n*144 + tid*3;
        float l0=lp[0], l1=lp[1], l2=lp[2];
        float* gp = ws + OFF_QG + n*144 + tid*3;
        for (int i=0;i<3;i++){ float g = R[i*3+0]*l0 + R[i*3+1]*l1 + R[i*3+2]*l2 + T[i]; gp[i]=g; qg_s[tid*3+i]=g; }
    } else if (tid < 96) {
        int u = tid-48;
        const float* lp = ws + OFF_KP + n*144 + u*3;
        float l0=lp[0], l1=lp[1], l2=lp[2];
        float* gp = ws + OFF_KG + n*144 + u*3;
        for (int i=0;i<3;i++){ float g = R[i*3+0]*l0 + R[i*3+1]*l1 + R[i*3+2]*l2 + T[i]; gp[i]=g; kg_s[u*3+i]=g; }
    } else {
        int u = tid-96;
        const float* lp = ws + OFF_VP + n*288 + u*3;
        float l0=lp[0], l1=lp[1], l2=lp[2];
        float* gp = ws + OFF_VG + n*288 + u*3;
        for (int i=0;i<3;i++){ float g = R[i*3+0]*l0 + R[i*3+1]*l1 + R[i*3+2]*l2 + T[i]; gp[i]=g; }
    }
    __syncthreads();
    if (tid < 12) {
        float a=0;
        for (int d=0; d<12; d++){ float x=qg_s[tid*12+d]; a+=x*x; }
        ws[OFF_QSQ + n*12 + tid]=a;
    } else if (tid < 24) {
        int h = tid-12; float a=0;
        for (int d=0; d<12; d++){ float x=kg_s[h*12+d]; a+=x*x; }
        ws[OFF_KSQ + n*12 + h]=a;
    }
}

// ---------------- Kernel 3: qk + point logits, per-head 64x64 tiles ----------
__global__ __launch_bounds__(256) void k_qkpt(
    const float* __restrict__ head_weights, float* __restrict__ ws)
{
    __shared__ float qs[QKD*QPAD], ks[QKD*QPAD], qa[64], kb[64];
    const int tid = threadIdx.x;
    const int m0 = blockIdx.x * 64, n0 = blockIdx.y * 64, h = blockIdx.z;
    const float hw = head_weights[h];
    for (int idx = tid; idx < 64*16; idx += 256) {
        int r = idx >> 4, c = idx & 15;
        qs[c*QPAD + r] = ws[OFF_Q + (n0+r)*192 + h*16 + c] * 0.25f;
        ks[c*QPAD + r] = ws[OFF_K + (m0+r)*192 + h*16 + c];
    }
    for (int idx = tid; idx < 64*12; idx += 256) {
        int r = idx / 12, c = idx % 12;
        qs[(16+c)*QPAD + r] = ws[OFF_QG + (n0+r)*144 + h*12 + c] * hw;
        ks[(16+c)*QPAD + r] = ws[OFF_KG + (m0+r)*144 + h*12 + c];
    }
    for (int idx = tid; idx < 64; idx += 256) {
        qa[idx] = -0.5f * hw * ws[OFF_QSQ + (n0+idx)*12 + h];
        kb[idx] = -0.5f * hw * ws[OFF_KSQ + (m0+idx)*12 + h];
    }
    __syncthreads();
    const int tx = tid & 15, ty = tid >> 4;
    float acc[4][4] = {{0.f}};
    #pragma unroll 4
    for (int d = 0; d < QKD; d++) {
        float4 a = *(const float4*)(qs + d*QPAD + ty*4);
        float4 b = *(const float4*)(ks + d*QPAD + tx*4);
        const float* ap = &a.x; const float* bp = &b.x;
        #pragma unroll
        for (int i=0;i<4;i++)
            #pragma unroll
            for (int j=0;j<4;j++) acc[i][j] += ap[i]*bp[j];
    }
    #pragma unroll
    for (int i=0;i<4;i++) {
        float ai = qa[ty*4+i];
        float4 r;
        r.x = acc[i][0] + ai + kb[tx*4+0];
        r.y = acc[i][1] + ai + kb[tx*4+1];
        r.z = acc[i][2] + ai + kb[tx*4+2];
        r.w = acc[i][3] + ai + kb[tx*4+3];
        *(float4*)(ws + OFF_LOG + ((size_t)(n0+ty*4+i)*H + h)*N + m0 + tx*4) = r;
    }
}

// ---------------- Kernel 4a: z@Wb + bb + dist + multiscale -> LOG (RMW) --------
// grid (4 mb, 512 n) x 256 thr = 2048 blocks. (R8 proven form, unchanged.)
__global__ __launch_bounds__(256) void k_zbias2(
    const float* __restrict__ z, const float* __restrict__ trans,
    const float* __restrict__ Wb, const float* __restrict__ bb,
    const float* __restrict__ dist_emb, const float* __restrict__ scale_logits,
    float* __restrict__ ws)
{
    __shared__ float zs[64*ZP2];         // 33.8 KB
    __shared__ float partial[4*64*13];   // 13.3 KB
    __shared__ float Wb_s[CZ*12];        // 6 KB
    __shared__ float sprob[36];
    const int mb = blockIdx.x, n = blockIdx.y;
    const int tid = threadIdx.x, lane = tid & 63, wave = tid >> 6;

    if (tid < 12) {
        float sa = scale_logits[tid], sb = scale_logits[12+tid], sc = scale_logits[24+tid];
        float mx = fmaxf(sa, fmaxf(sb, sc));
        float ea=__expf(sa-mx), eb=__expf(sb-mx), ec=__expf(sc-mx);
        float inv = 1.f/(ea+eb+ec);
        sprob[tid] = ea*inv; sprob[12+tid] = eb*inv; sprob[24+tid] = ec*inv;
    }
    for (int i = tid; i < 384; i += 256)
        *(float4*)(Wb_s + i*4) = *(const float4*)(Wb + i*4);
    __syncthreads();

    const float tnx = trans[n*3+0], tny = trans[n*3+1], tnz = trans[n*3+2];
    const int h0 = wave*3;

    for (int chunk = 0; chunk < 2; chunk++) {
        const int m0 = mb*128 + chunk*64;
        const float4* zsrc4 = (const float4*)(z + ((size_t)n*N + m0)*CZ);
        #pragma unroll
        for (int p = 0; p < 8; p++) {
            int idx = p*256 + tid;
            float4 v = zsrc4[idx];
            *(float4*)(zs + (idx>>5)*ZP2 + (idx&31)*4) = v;
        }
        __syncthreads();
        {
            const float* zrow = zs + lane*ZP2 + wave*32;
            float a[12];
            #pragma unroll
            for (int h=0;h<12;h++) a[h]=0.f;
            #pragma unroll
            for (int c4=0;c4<8;c4++) {
                float4 zq = *(const float4*)(zrow + c4*4);
                const float* wr = Wb_s + (wave*32 + c4*4)*12;
                const float* zp = &zq.x;
                #pragma unroll
                for (int j=0;j<4;j++) {
                    float4 w0 = *(const float4*)(wr + j*12);
                    float4 w1 = *(const float4*)(wr + j*12 + 4);
                    float4 w2 = *(const float4*)(wr + j*12 + 8);
                    float zj = zp[j];
                    a[0]+=zj*w0.x; a[1]+=zj*w0.y; a[2]+=zj*w0.z; a[3]+=zj*w0.w;
                    a[4]+=zj*w1.x; a[5]+=zj*w1.y; a[6]+=zj*w1.z; a[7]+=zj*w1.w;
                    a[8]+=zj*w2.x; a[9]+=zj*w2.y; a[10]+=zj*w2.z; a[11]+=zj*w2.w;
                }
            }
            float* pdst = partial + (wave*64 + lane)*13;
            #pragma unroll
            for (int h=0;h<12;h++) pdst[h] = a[h];
        }
        __syncthreads();
        {
            const int m = m0 + lane;
            float dx = tnx - trans[m*3+0];
            float dy = tny - trans[m*3+1];
            float dz = tnz - trans[m*3+2];
            float pdist = sqrtf(dx*dx+dy*dy+dz*dz);
            int bin = (int)ceilf(2.f*pdist) - 1;
            bin = bin < 0 ? 0 : (bin > NB-1 ? NB-1 : bin);
            const int ssel = (pdist <= 5.f) ? 0 : (pdist <= 15.f ? 1 : -1);
            float v0 = partial[(0*64+lane)*13 + h0]   + partial[(1*64+lane)*13 + h0]
                     + partial[(2*64+lane)*13 + h0]   + partial[(3*64+lane)*13 + h0];
            float v1 = partial[(0*64+lane)*13 + h0+1] + partial[(1*64+lane)*13 + h0+1]
                     + partial[(2*64+lane)*13 + h0+1] + partial[(3*64+lane)*13 + h0+1];
            float v2 = partial[(0*64+lane)*13 + h0+2] + partial[(1*64+lane)*13 + h0+2]
                     + partial[(2*64+lane)*13 + h0+2] + partial[(3*64+lane)*13 + h0+2];
            v0 += bb[h0]   + dist_emb[bin*12 + h0]   + sprob[24+h0];
            v1 += bb[h0+1] + dist_emb[bin*12 + h0+1] + sprob[24+h0+1];
            v2 += bb[h0+2] + dist_emb[bin*12 + h0+2] + sprob[24+h0+2];
            if (ssel == 0)      { v0 += sprob[h0];    v1 += sprob[h0+1];    v2 += sprob[h0+2]; }
            else if (ssel == 1) { v0 += sprob[12+h0]; v1 += sprob[12+h0+1]; v2 += sprob[12+h0+2]; }
            float* lp = ws + OFF_LOG + ((size_t)n*H + h0)*N + m;
            lp[0]   += v0;
            lp[N]   += v1;
            lp[2*N] += v2;
        }
        __syncthreads();
    }
}

// ---------------- Kernel 4b: role-split attn@z / attn@{V,VG}, softmax in LDS --
// grid (512 n, 2 roles) x 256 thr. Each role stages RAW biased logits and
// softmaxes its own LDS copy (k_sm dispatch + 25MB LOG RMW eliminated).
__global__ __launch_bounds__(256) void k_attnmm(
    const float* __restrict__ z, const float* __restrict__ trans,
    const float* __restrict__ rot, float* __restrict__ ws)
{
    __shared__ float attn_s[H*APAD];     // 24.2 KB
    __shared__ float part[4*12*64];      // 12 KB
    __shared__ float og_s[288];
    const int n = blockIdx.x, role = blockIdx.y, tid = threadIdx.x;
    const int lane = tid & 63, wave = tid >> 6;

    const float4* asrc = (const float4*)(ws + OFF_LOG + (size_t)n*H*N);
    for (int i = tid; i < H*(N/4); i += 256) {
        int h = i >> 7, q = i & 127;
        *(float4*)(attn_s + h*APAD + q*4) = asrc[h*128 + q];
    }
    __syncthreads();
    // softmax (wave per h-row) on the local copy
    for (int h = wave; h < H; h += 4) {
        float* row = attn_s + h*APAD;
        float v[8]; float mx = -1e30f;
        #pragma unroll
        for (int j=0;j<8;j++){ v[j]=row[lane + j*64]; mx = fmaxf(mx, v[j]); }
        #pragma unroll
        for (int off=32; off>0; off>>=1) mx = fmaxf(mx, __shfl_xor(mx, off, 64));
        float sum = 0.f;
        #pragma unroll
        for (int j=0;j<8;j++){ v[j]=__expf(v[j]-mx); sum += v[j]; }
        #pragma unroll
        for (int off=32; off>0; off>>=1) sum += __shfl_xor(sum, off, 64);
        float inv = 1.f/sum;
        #pragma unroll
        for (int j=0;j<8;j++) row[lane + j*64] = v[j]*inv;
    }
    __syncthreads();

    if (role == 0) {
        const int cq = tid & 15;
        const int ms = tid >> 4;
        for (int ch = 0; ch < 2; ch++) {
            const float* zb = z + (size_t)n*N*CZ + ch*64 + cq*4;
            float4 acc[12];
            #pragma unroll
            for (int h=0; h<12; h++) acc[h] = make_float4(0.f,0.f,0.f,0.f);
            const int r0 = ms*32;
            #pragma unroll 2
            for (int rq = 0; rq < 8; rq++) {
                const int r = r0 + rq*4;
                float4 z0 = *(const float4*)(zb + (size_t)(r+0)*CZ);
                float4 z1 = *(const float4*)(zb + (size_t)(r+1)*CZ);
                float4 z2 = *(const float4*)(zb + (size_t)(r+2)*CZ);
                float4 z3 = *(const float4*)(zb + (size_t)(r+3)*CZ);
                #pragma unroll
                for (int h=0; h<12; h++) {
                    float4 a4 = *(const float4*)(attn_s + h*APAD + r);
                    acc[h].x += a4.x*z0.x + a4.y*z1.x + a4.z*z2.x + a4.w*z3.x;
                    acc[h].y += a4.x*z0.y + a4.y*z1.y + a4.z*z2.y + a4.w*z3.y;
                    acc[h].z += a4.x*z0.z + a4.y*z1.z + a4.z*z2.z + a4.w*z3.z;
                    acc[h].w += a4.x*z0.w + a4.y*z1.w + a4.z*z2.w + a4.w*z3.w;
                }
            }
            #pragma unroll
            for (int h=0; h<12; h++) {
                acc[h].x += __shfl_xor(acc[h].x, 16, 64); acc[h].y += __shfl_xor(acc[h].y, 16, 64);
                acc[h].z += __shfl_xor(acc[h].z, 16, 64); acc[h].w += __shfl_xor(acc[h].w, 16, 64);
                acc[h].x += __shfl_xor(acc[h].x, 32, 64); acc[h].y += __shfl_xor(acc[h].y, 32, 64);
                acc[h].z += __shfl_xor(acc[h].z, 32, 64); acc[h].w += __shfl_xor(acc[h].w, 32, 64);
            }
            if (lane < 16) {
                #pragma unroll
                for (int h=0; h<12; h++)
                    *(float4*)(part + (wave*12 + h)*64 + lane*4) = acc[h];
            }
            __syncthreads();
            if (tid < 192) {
                const int h = tid >> 4, c4 = tid & 15;
                float4 s4 = *(const float4*)(part + (0*12 + h)*64 + c4*4);
                #pragma unroll
                for (int w=1; w<4; w++) {
                    float4 p = *(const float4*)(part + (w*12 + h)*64 + c4*4);
                    s4.x += p.x; s4.y += p.y; s4.z += p.z; s4.w += p.w;
                }
                *(float4*)(ws + OFF_FEAT + (size_t)n*2112 + h*176 + 48 + ch*64 + c4*4) = s4;
            }
            __syncthreads();
        }
    } else {
        if (tid < 240) {
            const int col4 = (tid % 120) * 4;
            const int msA  = tid / 120;
            const float* aptr; int astride, ah;
            if (col4 < 192) { ah = col4 >> 4;        aptr = ws + OFF_V  + col4;       astride = 192; }
            else            { ah = (col4-192) / 24;  aptr = ws + OFF_VG + (col4-192); astride = 288; }
            const float4* arow = (const float4*)(attn_s + ah*APAD);
            float4 acc = {0.f,0.f,0.f,0.f};
            #pragma unroll 2
            for (int mq = msA*64; mq < msA*64 + 64; mq++) {
                float4 a4 = arow[mq];
                const float* vp = aptr + (size_t)mq*4*astride;
                float4 v0 = *(const float4*)(vp);
                float4 v1 = *(const float4*)(vp + astride);
                float4 v2 = *(const float4*)(vp + 2*astride);
                float4 v3 = *(const float4*)(vp + 3*astride);
                acc.x += a4.x*v0.x + a4.y*v1.x + a4.z*v2.x + a4.w*v3.x;
                acc.y += a4.x*v0.y + a4.y*v1.y + a4.z*v2.y + a4.w*v3.y;
                acc.z += a4.x*v0.z + a4.y*v1.z + a4.z*v2.z + a4.w*v3.z;
                acc.w += a4.x*v0.w + a4.y*v1.w + a4.z*v2.w + a4.w*v3.w;
            }
            *(float4*)(part + tid*4) = acc;
        }
        __syncthreads();
        if (tid < 120) {
            const int col4 = tid * 4;
            float4 a = *(const float4*)(part + tid*4);
            float4 b = *(const float4*)(part + (tid+120)*4);
            a.x += b.x; a.y += b.y; a.z += b.z; a.w += b.w;
            if (col4 < 192) {
                const int ah = col4 >> 4;
                *(float4*)(ws + OFF_FEAT + (size_t)n*2112 + ah*176 + (col4 & 15)) = a;
            } else {
                *(float4*)(og_s + (col4 - 192)) = a;
            }
        }
        __syncthreads();
        if (tid < 96) {                          // rotate to local frame + norms
            const int h = tid >> 3, p = tid & 7;
            float g0 = og_s[h*24 + p*3 + 0] - trans[n*3+0];
            float g1 = og_s[h*24 + p*3 + 1] - trans[n*3+1];
            float g2 = og_s[h*24 + p*3 + 2] - trans[n*3+2];
            const float* R = rot + n*9;
            float* fdst = ws + OFF_FEAT + (size_t)n*2112 + h*176;
            float nsq = 0.f;
            #pragma unroll
            for (int i=0;i<3;i++){
                float l = R[0*3+i]*g0 + R[1*3+i]*g1 + R[2*3+i]*g2;   // R^T
                fdst[16 + p*3 + i] = l;
                nsq += l*l;
            }
            fdst[40 + p] = sqrtf(nsq);
        }
    }
}

// ---------------- Kernel 5: output GEMM (register-tiled), K split 4 ways -------
__global__ __launch_bounds__(256) void k_out(
    const float* __restrict__ Wout, const float* __restrict__ ws,
    float* __restrict__ out)
{
    __shared__ float f_s[16*KSP];        // 33.8 KB
    __shared__ float part[4*16*68];      // 17.4 KB
    const int tid = threadIdx.x;
    const int n0  = blockIdx.y * 16;
    const int k0  = blockIdx.z * KSP;
    const int cq  = tid & 15;
    const int rg  = (tid >> 4) & 3;
    const int ks  = tid >> 6;
    const int col = blockIdx.x * 64 + cq * 4;
    for (int i = tid; i < 16*KSP; i += 256) {
        int r = i / KSP, c = i - r*KSP;
        f_s[i] = ws[OFF_FEAT + (size_t)(n0 + r)*2112 + k0 + c];
    }
    __syncthreads();
    float acc[4][4] = {{0.f}};
    const float* wp = Wout + (size_t)(k0 + ks*132)*CS + col;
    const float* f0 = f_s + (rg*4)*KSP + ks*132;
    #pragma unroll 4
    for (int kk = 0; kk < 132; kk++) {
        float4 w4 = *(const float4*)(wp + (size_t)kk*CS);
        #pragma unroll
        for (int r = 0; r < 4; r++) {
            float fv = f0[r*KSP + kk];
            acc[r][0] += fv*w4.x; acc[r][1] += fv*w4.y;
            acc[r][2] += fv*w4.z; acc[r][3] += fv*w4.w;
        }
    }
    #pragma unroll
    for (int r = 0; r < 4; r++)
        *(float4*)(part + (ks*16 + rg*4 + r)*68 + cq*4) =
            make_float4(acc[r][0], acc[r][1], acc[r][2], acc[r][3]);
    __syncthreads();
    {
        const int row = tid >> 4;
        float4 s = *(const float4*)(part + (0*16 + row)*68 + cq*4);
        #pragma unroll
        for (int k2 = 1; k2 < 4; k2++) {
            float4 p = *(const float4*)(part + (k2*16 + row)*68 + cq*4);
            s.x += p.x; s.y += p.y; s.z += p.z; s.w += p.w;
        }
        float* o = out + (size_t)(n0+row)*CS + col;
        atomicAdd(o+0, s.x); atomicAdd(o+1, s.y);
        atomicAdd(o+2, s.z); atomicAdd(o+3, s.w);
    }
}

extern "C" void kernel_launch(void* const* d_in, const int* in_sizes, int n_in,
                              void* d_out, int out_size, void* d_ws, size_t ws_size,
                              hipStream_t stream) {
    const float* s     = (const float*)d_in[0];
    const float* z     = (const float*)d_in[1];
    const float* trans = (const float*)d_in[2];
    const float* rot   = (const float*)d_in[3];
    const float* Wq  = (const float*)d_in[5];  const float* bq  = (const float*)d_in[6];
    const float* Wk  = (const float*)d_in[7];  const float* bk  = (const float*)d_in[8];
    const float* Wv  = (const float*)d_in[9];  const float* bv  = (const float*)d_in[10];
    const float* Wqp = (const float*)d_in[11]; const float* bqp = (const float*)d_in[12];
    const float* Wkp = (const float*)d_in[13]; const float* bkp = (const float*)d_in[14];
    const float* Wvp = (const float*)d_in[15]; const float* bvp = (const float*)d_in[16];
    const float* Wb  = (const float*)d_in[17]; const float* bb  = (const float*)d_in[18];
    const float* dist_emb     = (const float*)d_in[19];
    const float* scale_logits = (const float*)d_in[20];
    const float* head_weights = (const float*)d_in[21];
    const float* Wout = (const float*)d_in[22]; const float* bout = (const float*)d_in[23];
    float* out = (float*)d_out;
    float* ws  = (float*)d_ws;

    k_proj<<<dim3(18, 32), 256, 0, stream>>>(s, Wq,bq, Wk,bk, Wv,bv, Wqp,bqp, Wkp,bkp, Wvp,bvp, ws);
    k_frames<<<N, 192, 0, stream>>>(rot, trans, bout, out, ws);
    k_qkpt<<<dim3(8, 8, 12), 256, 0, stream>>>(head_weights, ws);
    k_zbias2<<<dim3(4, N), 256, 0, stream>>>(z, trans, Wb, bb, dist_emb, scale_logits, ws);
    k_attnmm<<<dim3(N, 2), 256, 0, stream>>>(z, trans, rot, ws);
    k_out<<<dim3(6, 32, 4), 256, 0, stream>>>(Wout, ws, out);
}